// Round 16
// baseline (139.516 us; speedup 1.0000x reference)
//
#include <hip/hip_runtime.h>

#define IN_DIM  65536
#define OUT_DIM 65536
#define BATCH   256

// ws layout: float4 coeffs[OUT_DIM] @256 ; uint x_Tb[IN_DIM * BATCH/2] @2MiB (packed bf16 pairs).

// clang-native vector types: __builtin_nontemporal_load requires ext_vector
// types (HIP_vector_type float4/uint2 are class types and are rejected).
typedef float        f32x4 __attribute__((ext_vector_type(4)));
typedef unsigned int u32x2 __attribute__((ext_vector_type(2)));

__device__ __forceinline__ float bf2f(unsigned short h) {
    return __uint_as_float(((unsigned int)h) << 16);
}
__device__ __forceinline__ unsigned short f2bf(float f) {
    unsigned int u = __float_as_uint(f);
    u += 0x7FFFu + ((u >> 16) & 1u);
    return (unsigned short)(u >> 16);
}

// Softmax over 16 logits collapsed to affine coeffs of out = w0 + w1*a + w2*b + w3*ab.
__device__ __forceinline__ float4 collapse16(const float* w) {
    float m = w[0];
    #pragma unroll
    for (int f = 1; f < 16; ++f) m = fmaxf(m, w[f]);
    float e[16]; float sum = 0.f;
    #pragma unroll
    for (int f = 0; f < 16; ++f) { e[f] = __expf(w[f] - m); sum += e[f]; }
    float inv = 1.0f / sum;
    float w0 = e[8] + e[9] + e[10] + e[11] + e[12] + e[13] + e[14] + e[15];
    float w1 = (e[2] + e[3] + e[6] + e[7]) - (e[8] + e[9] + e[12] + e[13]);
    float w2 = (e[4] + e[5] + e[6] + e[7]) - (e[8] + e[9] + e[10] + e[11]);
    float w3 = e[1] - e[2] - e[4] - 2.f*e[6] - e[7]
             + e[8] + 2.f*e[9] + e[11] + e[13] - e[14];
    return make_float4(w0 * inv, w1 * inv, w2 * inv, w3 * inv);
}

#define TRANS_BLOCKS ((IN_DIM / 64) * (BATCH / 64))   // 4096
#define COEFF_BLOCKS (OUT_DIM / 256)                  // 256
#define PAD 69   // 69 % 32 = 5 -> column-phase reads are <=2-way (free)

// ---------------------------------------------------------------------------
// R13: R10 structure (135.3 us) + NON-TEMPORAL loads for the one-shot
// streams (x in prep, idx in logic), now via clang ext_vector types so the
// builtin compiles (R15 compile-error fix). x is read exactly once; NT
// keeps its 64 MiB stream from evicting x_Tb lines that the logic kernel's
// gather wants L2/L3-resident. Gather loads stay REGULAR (x_Tb lines are
// reused). Everything else identical to R10.
// ---------------------------------------------------------------------------

// Kernel A: fused transpose (x [BATCH,IN_DIM] -> packed-bf16 x_Tb) + coeffs.
__global__ __launch_bounds__(256) void prep_kernel(
    const void* __restrict__ x_raw,       // [BATCH, IN_DIM] fp32 or bf16
    const void* __restrict__ w_raw,       // [OUT_DIM, 16]   fp32 or bf16
    unsigned int* __restrict__ x_Tb,      // [IN_DIM, BATCH/2] packed bf16
    float4* __restrict__ coeffs,          // [OUT_DIM]
    int trans_blocks)
{
    __shared__ float tile[64][PAD];       // [batch_row][col]
    __shared__ int sflag;
    int t  = threadIdx.x;
    int bx = blockIdx.x;

    if (bx < trans_blocks) {
        if (t == 0) sflag = 0;
        __syncthreads();
        if (((const unsigned short*)x_raw)[t] >= 0x3F80u) atomicOr(&sflag, 1);
        __syncthreads();
        int x_is_f32 = sflag;

        int c0 = (bx >> 2) * 64;   // input-dim tile
        int b0 = (bx & 3) * 64;    // batch tile
        int cq = t & 15;           // float4 col group (4 cols)
        int r  = t >> 4;           // 0..15

        if (x_is_f32) {
            const f32x4* x4 = (const f32x4*)x_raw;
            #pragma unroll
            for (int k = 0; k < 4; ++k) {
                int row = r + 16 * k;
                f32x4 v = __builtin_nontemporal_load(
                    &x4[(size_t)(b0 + row) * (IN_DIM / 4) + (c0 >> 2) + cq]);
                tile[row][4 * cq + 0] = v.x;
                tile[row][4 * cq + 1] = v.y;
                tile[row][4 * cq + 2] = v.z;
                tile[row][4 * cq + 3] = v.w;
            }
        } else {
            const u32x2* x2 = (const u32x2*)x_raw;  // 4 bf16 per u32x2
            #pragma unroll
            for (int k = 0; k < 4; ++k) {
                int row = r + 16 * k;
                u32x2 v = __builtin_nontemporal_load(
                    &x2[(size_t)(b0 + row) * (IN_DIM / 4) + (c0 >> 2) + cq]);
                tile[row][4 * cq + 0] = bf2f((unsigned short)(v.x & 0xFFFFu));
                tile[row][4 * cq + 1] = bf2f((unsigned short)(v.x >> 16));
                tile[row][4 * cq + 2] = bf2f((unsigned short)(v.y & 0xFFFFu));
                tile[row][4 * cq + 3] = bf2f((unsigned short)(v.y >> 16));
            }
        }
        __syncthreads();

        // pack columns: per col, 32 dwords (64 batch) = 8 uint4; 512 uint4/tile
        uint4* dst = (uint4*)x_Tb;
        int q   = t & 7;          // uint4 index within col (batch 8q..8q+7)
        int col = t >> 3;         // 0..31, second iter +32
        #pragma unroll
        for (int it = 0; it < 2; ++it) {
            int cc = col + 32 * it;
            unsigned int d[4];
            #pragma unroll
            for (int j = 0; j < 4; ++j) {
                float lo = tile[8 * q + 2 * j][cc];
                float hi = tile[8 * q + 2 * j + 1][cc];
                d[j] = (unsigned int)f2bf(lo) | ((unsigned int)f2bf(hi) << 16);
            }
            dst[(size_t)(c0 + cc) * (BATCH / 8) + (b0 >> 3) + q] =
                make_uint4(d[0], d[1], d[2], d[3]);
        }
    } else {
        // ---- coeff block ----
        if (t == 0) sflag = 0;
        __syncthreads();
        if ((((const unsigned short*)w_raw)[t] & 0x7FFFu) >= 0x4800u) atomicOr(&sflag, 1);
        __syncthreads();
        int w_is_f32 = sflag;

        int o = (bx - trans_blocks) * 256 + t;
        if (o >= OUT_DIM) return;

        float w[16];
        if (w_is_f32) {
            const float4* w4 = reinterpret_cast<const float4*>(w_raw) + (size_t)o * 4;
            float4 q0 = w4[0], q1 = w4[1], q2 = w4[2], q3 = w4[3];
            w[0]=q0.x; w[1]=q0.y; w[2]=q0.z; w[3]=q0.w;
            w[4]=q1.x; w[5]=q1.y; w[6]=q1.z; w[7]=q1.w;
            w[8]=q2.x; w[9]=q2.y; w[10]=q2.z; w[11]=q2.w;
            w[12]=q3.x; w[13]=q3.y; w[14]=q3.z; w[15]=q3.w;
        } else {
            const uint4* w16 = reinterpret_cast<const uint4*>(
                (const unsigned short*)w_raw + (size_t)o * 16);
            uint4 p0 = w16[0], p1 = w16[1];
            unsigned int pk[8] = { p0.x, p0.y, p0.z, p0.w, p1.x, p1.y, p1.z, p1.w };
            #pragma unroll
            for (int i = 0; i < 8; ++i) {
                w[2*i]   = bf2f((unsigned short)(pk[i] & 0xFFFFu));
                w[2*i+1] = bf2f((unsigned short)(pk[i] >> 16));
            }
        }
        coeffs[o] = collapse16(w);
    }
}

// ---------------------------------------------------------------------------
// Kernel B (halftile, R10-proven): block owns 32 neurons x 128-batch half.
// 64 rows x 256B gathered coalesced into 16 KiB XOR-swizzled LDS
// (phys = l ^ (r&15)). 8 blocks/CU. Coalesced NT stores.
// ---------------------------------------------------------------------------
__global__ __launch_bounds__(256, 8) void logic_bt_kernel(
    const unsigned int* __restrict__ x_Tb,  // [IN_DIM, BATCH/2]
    const void* __restrict__ idx_raw,       // [2, OUT_DIM] int32 or int64
    const float4* __restrict__ coeffs,
    float* __restrict__ out)                // [BATCH, OUT_DIM]
{
    __shared__ uint4 rows4[64 * 16];        // 16 KiB
    __shared__ int sflag;
    int t = threadIdx.x;
    if (t == 0) sflag = 0;
    __syncthreads();
    if ((t & 1) && ((const int*)idx_raw)[t] != 0) atomicOr(&sflag, 1);
    __syncthreads();
    int idx_is_i32 = sflag;   // odd dwords nonzero -> int32

    int lt = blockIdx.x;
    int o0 = (lt >> 1) * 32;
    int hc = (lt & 1) * 16;   // uint4 col offset within full row
    int rr = t >> 4;          // 0..15: row within pass
    int l  = t & 15;          // uint4 slot within 256B half-row

    int wires[4];
    if (idx_is_i32) {
        const int* p = (const int*)idx_raw;
        #pragma unroll
        for (int ps = 0; ps < 4; ++ps) {
            int r = rr + 16 * ps;                // 0..63
            wires[ps] = __builtin_nontemporal_load(
                &p[(r >> 5) * OUT_DIM + o0 + (r & 31)]);
        }
    } else {
        const long long* p = (const long long*)idx_raw;
        #pragma unroll
        for (int ps = 0; ps < 4; ++ps) {
            int r = rr + 16 * ps;
            wires[ps] = (int)__builtin_nontemporal_load(
                &p[(r >> 5) * OUT_DIM + o0 + (r & 31)]);
        }
    }

    // load-all-then-write-all: 4 independent gathers in flight per thread
    const uint4* src4 = (const uint4*)x_Tb;
    uint4 v[4];
    #pragma unroll
    for (int ps = 0; ps < 4; ++ps)
        v[ps] = src4[(size_t)wires[ps] * (BATCH / 8) + hc + l];
    float4 c = coeffs[o0 + (t & 31)];
    #pragma unroll
    for (int ps = 0; ps < 4; ++ps) {
        int r = rr + 16 * ps;
        rows4[r * 16 + (l ^ (r & 15))] = v[ps];
    }
    __syncthreads();

    int o = t & 31;           // neuron within tile
    const uint4* ra4 = rows4 + o * 16;
    const uint4* rb4 = rows4 + (32 + o) * 16;
    float* outp = out + o0 + o;
    int B0 = (lt & 1) * 128;
    #pragma unroll
    for (int i = 0; i < 2; ++i) {
        int bq = (t >> 5) + 8 * i;      // batch quad within half: 0..15
        uint4 ua = ra4[bq ^ (o & 15)];
        uint4 ub = rb4[bq ^ (o & 15)];
        unsigned int pa[4] = { ua.x, ua.y, ua.z, ua.w };
        unsigned int pb[4] = { ub.x, ub.y, ub.z, ub.w };
        int base = B0 + bq * 8;
        #pragma unroll
        for (int j = 0; j < 4; ++j) {
            float a0 = bf2f((unsigned short)(pa[j] & 0xFFFFu));
            float a1 = bf2f((unsigned short)(pa[j] >> 16));
            float v0 = bf2f((unsigned short)(pb[j] & 0xFFFFu));
            float v1 = bf2f((unsigned short)(pb[j] >> 16));
            float r0v = fmaf(v0, fmaf(c.w, a0, c.z), fmaf(c.y, a0, c.x));
            float r1v = fmaf(v1, fmaf(c.w, a1, c.z), fmaf(c.y, a1, c.x));
            __builtin_nontemporal_store(r0v, outp + (size_t)(base + 2*j)     * OUT_DIM);
            __builtin_nontemporal_store(r1v, outp + (size_t)(base + 2*j + 1) * OUT_DIM);
        }
    }
}

// ---------------------------------------------------------------------------
// Fallback: direct gather from row-major x (only if ws can't hold x_Tb).
// ---------------------------------------------------------------------------
__global__ __launch_bounds__(256) void logic_direct_kernel(
    const void* __restrict__ x_raw,
    const void* __restrict__ idx_raw,
    const float4* __restrict__ coeffs,
    float* __restrict__ out)
{
    __shared__ int sflag;
    int t = threadIdx.x;
    if (t == 0) sflag = 0;
    __syncthreads();
    int fl = 0;
    if (((const unsigned short*)x_raw)[t] >= 0x3F80u) fl |= 1;
    if ((t & 1) && ((const int*)idx_raw)[t] != 0) fl |= 2;
    if (fl) atomicOr(&sflag, fl);
    __syncthreads();
    int x_is_f32   = sflag & 1;
    int idx_is_i32 = (sflag >> 1) & 1;

    int o = blockIdx.x * 256 + t;
    int ia, ib;
    if (idx_is_i32) {
        const int* p = (const int*)idx_raw;
        ia = p[o];       ib = p[OUT_DIM + o];
    } else {
        const long long* p = (const long long*)idx_raw;
        ia = (int)p[o];  ib = (int)p[OUT_DIM + o];
    }
    float4 c = coeffs[o];
    int b0 = blockIdx.y * 32;

    if (x_is_f32) {
        const float* xa = (const float*)x_raw + ia;
        const float* xb = (const float*)x_raw + ib;
        #pragma unroll 8
        for (int r = 0; r < 32; ++r) {
            int b = b0 + r;
            float av = xa[(size_t)b * IN_DIM];
            float bv = xb[(size_t)b * IN_DIM];
            out[(size_t)b * OUT_DIM + o] =
                fmaf(bv, fmaf(c.w, av, c.z), fmaf(c.y, av, c.x));
        }
    } else {
        const unsigned short* xa = (const unsigned short*)x_raw + ia;
        const unsigned short* xb = (const unsigned short*)x_raw + ib;
        #pragma unroll 8
        for (int r = 0; r < 32; ++r) {
            int b = b0 + r;
            float av = bf2f(xa[(size_t)b * IN_DIM]);
            float bv = bf2f(xb[(size_t)b * IN_DIM]);
            out[(size_t)b * OUT_DIM + o] =
                fmaf(bv, fmaf(c.w, av, c.z), fmaf(c.y, av, c.x));
        }
    }
}

extern "C" void kernel_launch(void* const* d_in, const int* in_sizes, int n_in,
                              void* d_out, int out_size, void* d_ws, size_t ws_size,
                              hipStream_t stream) {
    const void* x       = d_in[0];
    const void* weights = d_in[1];
    const void* indices = d_in[2];
    float*      out     = (float*)d_out;

    float4*       coeffs = (float4*)((char*)d_ws + 256);
    unsigned int* x_Tb   = (unsigned int*)((char*)d_ws + 2u * 1024u * 1024u);

    const size_t need = 2u * 1024u * 1024u +
                        (size_t)IN_DIM * (BATCH / 2) * sizeof(unsigned int); // ~34 MiB

    if (ws_size >= need) {
        prep_kernel<<<dim3(TRANS_BLOCKS + COEFF_BLOCKS), dim3(256), 0, stream>>>(
            x, weights, x_Tb, coeffs, TRANS_BLOCKS);
        logic_bt_kernel<<<dim3((OUT_DIM / 32) * 2), dim3(256), 0, stream>>>(
            x_Tb, indices, coeffs, out);
    } else {
        prep_kernel<<<dim3(COEFF_BLOCKS), dim3(256), 0, stream>>>(
            x, weights, x_Tb, coeffs, /*trans_blocks=*/0);
        dim3 grid(OUT_DIM / 256, BATCH / 32);
        logic_direct_kernel<<<grid, dim3(256), 0, stream>>>(
            x, indices, coeffs, out);
    }
}

// Round 17
// 137.342 us; speedup vs baseline: 1.0158x; 1.0158x over previous
//
#include <hip/hip_runtime.h>

#define IN_DIM  65536
#define OUT_DIM 65536
#define BATCH   256

// ws layout: float4 coeffs[OUT_DIM] @256 ; uint x_Tb[IN_DIM * BATCH/2] @2MiB (packed bf16 pairs).

__device__ __forceinline__ float bf2f(unsigned short h) {
    return __uint_as_float(((unsigned int)h) << 16);
}
__device__ __forceinline__ unsigned short f2bf(float f) {
    unsigned int u = __float_as_uint(f);
    u += 0x7FFFu + ((u >> 16) & 1u);
    return (unsigned short)(u >> 16);
}

// Softmax over 16 logits collapsed to affine coeffs of out = w0 + w1*a + w2*b + w3*ab.
__device__ __forceinline__ float4 collapse16(const float* w) {
    float m = w[0];
    #pragma unroll
    for (int f = 1; f < 16; ++f) m = fmaxf(m, w[f]);
    float e[16]; float sum = 0.f;
    #pragma unroll
    for (int f = 0; f < 16; ++f) { e[f] = __expf(w[f] - m); sum += e[f]; }
    float inv = 1.0f / sum;
    float w0 = e[8] + e[9] + e[10] + e[11] + e[12] + e[13] + e[14] + e[15];
    float w1 = (e[2] + e[3] + e[6] + e[7]) - (e[8] + e[9] + e[12] + e[13]);
    float w2 = (e[4] + e[5] + e[6] + e[7]) - (e[8] + e[9] + e[10] + e[11]);
    float w3 = e[1] - e[2] - e[4] - 2.f*e[6] - e[7]
             + e[8] + 2.f*e[9] + e[11] + e[13] - e[14];
    return make_float4(w0 * inv, w1 * inv, w2 * inv, w3 * inv);
}

#define TRANS_BLOCKS ((IN_DIM / 64) * (BATCH / 64))   // 4096
#define COEFF_BLOCKS (OUT_DIM / 256)                  // 256
#define PAD 69   // 69 % 32 = 5 -> column-phase reads are <=2-way (free)

// ---------------------------------------------------------------------------
// R14: exact revert to the R10 kernel (measured 135.3 us, session best).
// R16 falsified the NT-load theory (nt on one-shot x/idx reads cost +4.2 us)
// -> reverted. Session ledger:
//   R5-shape gather + grid.y=8:          139.0
//   staged fulltile gather (32KiB LDS):  137.6
//   halftile 8 blocks/CU + MLP staging:  135.3  <- this kernel
//   + NT loads on x/idx:                 139.5  (reverted)
//   fused resident-grid (3 variants):    245-450 (abandoned; grid-barrier
//     phase-2 gather is pathological on XCD-partitioned L2)
// Remaining time is harness fill (~42us @ 80% HBM peak), dispatch edges
// (~16us each, irreducible without fusion), and kernels at ~1.7x their
// pure-traffic floor from random-L3-gather latency (TLP probe: +2.3us only).
// ---------------------------------------------------------------------------

// Kernel A: fused transpose (x [BATCH,IN_DIM] -> packed-bf16 x_Tb) + coeffs.
__global__ __launch_bounds__(256) void prep_kernel(
    const void* __restrict__ x_raw,       // [BATCH, IN_DIM] fp32 or bf16
    const void* __restrict__ w_raw,       // [OUT_DIM, 16]   fp32 or bf16
    unsigned int* __restrict__ x_Tb,      // [IN_DIM, BATCH/2] packed bf16
    float4* __restrict__ coeffs,          // [OUT_DIM]
    int trans_blocks)
{
    __shared__ float tile[64][PAD];       // [batch_row][col]
    __shared__ int sflag;
    int t  = threadIdx.x;
    int bx = blockIdx.x;

    if (bx < trans_blocks) {
        if (t == 0) sflag = 0;
        __syncthreads();
        if (((const unsigned short*)x_raw)[t] >= 0x3F80u) atomicOr(&sflag, 1);
        __syncthreads();
        int x_is_f32 = sflag;

        int c0 = (bx >> 2) * 64;   // input-dim tile
        int b0 = (bx & 3) * 64;    // batch tile
        int cq = t & 15;           // float4 col group (4 cols)
        int r  = t >> 4;           // 0..15

        if (x_is_f32) {
            const float4* x4 = (const float4*)x_raw;
            #pragma unroll
            for (int k = 0; k < 4; ++k) {
                int row = r + 16 * k;
                float4 v = x4[(size_t)(b0 + row) * (IN_DIM / 4) + (c0 >> 2) + cq];
                tile[row][4 * cq + 0] = v.x;
                tile[row][4 * cq + 1] = v.y;
                tile[row][4 * cq + 2] = v.z;
                tile[row][4 * cq + 3] = v.w;
            }
        } else {
            const uint2* x2 = (const uint2*)x_raw;  // 4 bf16 per uint2
            #pragma unroll
            for (int k = 0; k < 4; ++k) {
                int row = r + 16 * k;
                uint2 v = x2[(size_t)(b0 + row) * (IN_DIM / 4) + (c0 >> 2) + cq];
                tile[row][4 * cq + 0] = bf2f((unsigned short)(v.x & 0xFFFFu));
                tile[row][4 * cq + 1] = bf2f((unsigned short)(v.x >> 16));
                tile[row][4 * cq + 2] = bf2f((unsigned short)(v.y & 0xFFFFu));
                tile[row][4 * cq + 3] = bf2f((unsigned short)(v.y >> 16));
            }
        }
        __syncthreads();

        // pack columns: per col, 32 dwords (64 batch) = 8 uint4; 512 uint4/tile
        uint4* dst = (uint4*)x_Tb;
        int q   = t & 7;          // uint4 index within col (batch 8q..8q+7)
        int col = t >> 3;         // 0..31, second iter +32
        #pragma unroll
        for (int it = 0; it < 2; ++it) {
            int cc = col + 32 * it;
            unsigned int d[4];
            #pragma unroll
            for (int j = 0; j < 4; ++j) {
                float lo = tile[8 * q + 2 * j][cc];
                float hi = tile[8 * q + 2 * j + 1][cc];
                d[j] = (unsigned int)f2bf(lo) | ((unsigned int)f2bf(hi) << 16);
            }
            dst[(size_t)(c0 + cc) * (BATCH / 8) + (b0 >> 3) + q] =
                make_uint4(d[0], d[1], d[2], d[3]);
        }
    } else {
        // ---- coeff block ----
        if (t == 0) sflag = 0;
        __syncthreads();
        if ((((const unsigned short*)w_raw)[t] & 0x7FFFu) >= 0x4800u) atomicOr(&sflag, 1);
        __syncthreads();
        int w_is_f32 = sflag;

        int o = (bx - trans_blocks) * 256 + t;
        if (o >= OUT_DIM) return;

        float w[16];
        if (w_is_f32) {
            const float4* w4 = reinterpret_cast<const float4*>(w_raw) + (size_t)o * 4;
            float4 q0 = w4[0], q1 = w4[1], q2 = w4[2], q3 = w4[3];
            w[0]=q0.x; w[1]=q0.y; w[2]=q0.z; w[3]=q0.w;
            w[4]=q1.x; w[5]=q1.y; w[6]=q1.z; w[7]=q1.w;
            w[8]=q2.x; w[9]=q2.y; w[10]=q2.z; w[11]=q2.w;
            w[12]=q3.x; w[13]=q3.y; w[14]=q3.z; w[15]=q3.w;
        } else {
            const uint4* w16 = reinterpret_cast<const uint4*>(
                (const unsigned short*)w_raw + (size_t)o * 16);
            uint4 p0 = w16[0], p1 = w16[1];
            unsigned int pk[8] = { p0.x, p0.y, p0.z, p0.w, p1.x, p1.y, p1.z, p1.w };
            #pragma unroll
            for (int i = 0; i < 8; ++i) {
                w[2*i]   = bf2f((unsigned short)(pk[i] & 0xFFFFu));
                w[2*i+1] = bf2f((unsigned short)(pk[i] >> 16));
            }
        }
        coeffs[o] = collapse16(w);
    }
}

// ---------------------------------------------------------------------------
// Kernel B (halftile): block owns 32 neurons x 128-batch half.
// 64 rows x 256B gathered coalesced (16 lanes x 16B per row, full 128B
// lines, each half-row touched once) into 16 KiB XOR-swizzled LDS
// (phys = l ^ (r&15)). 8 blocks/CU. Coalesced NT stores.
// ---------------------------------------------------------------------------
__global__ __launch_bounds__(256, 8) void logic_bt_kernel(
    const unsigned int* __restrict__ x_Tb,  // [IN_DIM, BATCH/2]
    const void* __restrict__ idx_raw,       // [2, OUT_DIM] int32 or int64
    const float4* __restrict__ coeffs,
    float* __restrict__ out)                // [BATCH, OUT_DIM]
{
    __shared__ uint4 rows4[64 * 16];        // 16 KiB
    __shared__ int sflag;
    int t = threadIdx.x;
    if (t == 0) sflag = 0;
    __syncthreads();
    if ((t & 1) && ((const int*)idx_raw)[t] != 0) atomicOr(&sflag, 1);
    __syncthreads();
    int idx_is_i32 = sflag;   // odd dwords nonzero -> int32

    int lt = blockIdx.x;
    int o0 = (lt >> 1) * 32;
    int hc = (lt & 1) * 16;   // uint4 col offset within full row
    int rr = t >> 4;          // 0..15: row within pass
    int l  = t & 15;          // uint4 slot within 256B half-row

    int wires[4];
    if (idx_is_i32) {
        const int* p = (const int*)idx_raw;
        #pragma unroll
        for (int ps = 0; ps < 4; ++ps) {
            int r = rr + 16 * ps;                // 0..63
            wires[ps] = p[(r >> 5) * OUT_DIM + o0 + (r & 31)];
        }
    } else {
        const long long* p = (const long long*)idx_raw;
        #pragma unroll
        for (int ps = 0; ps < 4; ++ps) {
            int r = rr + 16 * ps;
            wires[ps] = (int)p[(r >> 5) * OUT_DIM + o0 + (r & 31)];
        }
    }

    // load-all-then-write-all: 4 independent gathers in flight per thread
    const uint4* src4 = (const uint4*)x_Tb;
    uint4 v[4];
    #pragma unroll
    for (int ps = 0; ps < 4; ++ps)
        v[ps] = src4[(size_t)wires[ps] * (BATCH / 8) + hc + l];
    float4 c = coeffs[o0 + (t & 31)];
    #pragma unroll
    for (int ps = 0; ps < 4; ++ps) {
        int r = rr + 16 * ps;
        rows4[r * 16 + (l ^ (r & 15))] = v[ps];
    }
    __syncthreads();

    int o = t & 31;           // neuron within tile
    const uint4* ra4 = rows4 + o * 16;
    const uint4* rb4 = rows4 + (32 + o) * 16;
    float* outp = out + o0 + o;
    int B0 = (lt & 1) * 128;
    #pragma unroll
    for (int i = 0; i < 2; ++i) {
        int bq = (t >> 5) + 8 * i;      // batch quad within half: 0..15
        uint4 ua = ra4[bq ^ (o & 15)];
        uint4 ub = rb4[bq ^ (o & 15)];
        unsigned int pa[4] = { ua.x, ua.y, ua.z, ua.w };
        unsigned int pb[4] = { ub.x, ub.y, ub.z, ub.w };
        int base = B0 + bq * 8;
        #pragma unroll
        for (int j = 0; j < 4; ++j) {
            float a0 = bf2f((unsigned short)(pa[j] & 0xFFFFu));
            float a1 = bf2f((unsigned short)(pa[j] >> 16));
            float v0 = bf2f((unsigned short)(pb[j] & 0xFFFFu));
            float v1 = bf2f((unsigned short)(pb[j] >> 16));
            float r0v = fmaf(v0, fmaf(c.w, a0, c.z), fmaf(c.y, a0, c.x));
            float r1v = fmaf(v1, fmaf(c.w, a1, c.z), fmaf(c.y, a1, c.x));
            __builtin_nontemporal_store(r0v, outp + (size_t)(base + 2*j)     * OUT_DIM);
            __builtin_nontemporal_store(r1v, outp + (size_t)(base + 2*j + 1) * OUT_DIM);
        }
    }
}

// ---------------------------------------------------------------------------
// Fallback: direct gather from row-major x (only if ws can't hold x_Tb).
// ---------------------------------------------------------------------------
__global__ __launch_bounds__(256) void logic_direct_kernel(
    const void* __restrict__ x_raw,
    const void* __restrict__ idx_raw,
    const float4* __restrict__ coeffs,
    float* __restrict__ out)
{
    __shared__ int sflag;
    int t = threadIdx.x;
    if (t == 0) sflag = 0;
    __syncthreads();
    int fl = 0;
    if (((const unsigned short*)x_raw)[t] >= 0x3F80u) fl |= 1;
    if ((t & 1) && ((const int*)idx_raw)[t] != 0) fl |= 2;
    if (fl) atomicOr(&sflag, fl);
    __syncthreads();
    int x_is_f32   = sflag & 1;
    int idx_is_i32 = (sflag >> 1) & 1;

    int o = blockIdx.x * 256 + t;
    int ia, ib;
    if (idx_is_i32) {
        const int* p = (const int*)idx_raw;
        ia = p[o];       ib = p[OUT_DIM + o];
    } else {
        const long long* p = (const long long*)idx_raw;
        ia = (int)p[o];  ib = (int)p[OUT_DIM + o];
    }
    float4 c = coeffs[o];
    int b0 = blockIdx.y * 32;

    if (x_is_f32) {
        const float* xa = (const float*)x_raw + ia;
        const float* xb = (const float*)x_raw + ib;
        #pragma unroll 8
        for (int r = 0; r < 32; ++r) {
            int b = b0 + r;
            float av = xa[(size_t)b * IN_DIM];
            float bv = xb[(size_t)b * IN_DIM];
            out[(size_t)b * OUT_DIM + o] =
                fmaf(bv, fmaf(c.w, av, c.z), fmaf(c.y, av, c.x));
        }
    } else {
        const unsigned short* xa = (const unsigned short*)x_raw + ia;
        const unsigned short* xb = (const unsigned short*)x_raw + ib;
        #pragma unroll 8
        for (int r = 0; r < 32; ++r) {
            int b = b0 + r;
            float av = bf2f(xa[(size_t)b * IN_DIM]);
            float bv = bf2f(xb[(size_t)b * IN_DIM]);
            out[(size_t)b * OUT_DIM + o] =
                fmaf(bv, fmaf(c.w, av, c.z), fmaf(c.y, av, c.x));
        }
    }
}

extern "C" void kernel_launch(void* const* d_in, const int* in_sizes, int n_in,
                              void* d_out, int out_size, void* d_ws, size_t ws_size,
                              hipStream_t stream) {
    const void* x       = d_in[0];
    const void* weights = d_in[1];
    const void* indices = d_in[2];
    float*      out     = (float*)d_out;

    float4*       coeffs = (float4*)((char*)d_ws + 256);
    unsigned int* x_Tb   = (unsigned int*)((char*)d_ws + 2u * 1024u * 1024u);

    const size_t need = 2u * 1024u * 1024u +
                        (size_t)IN_DIM * (BATCH / 2) * sizeof(unsigned int); // ~34 MiB

    if (ws_size >= need) {
        prep_kernel<<<dim3(TRANS_BLOCKS + COEFF_BLOCKS), dim3(256), 0, stream>>>(
            x, weights, x_Tb, coeffs, TRANS_BLOCKS);
        logic_bt_kernel<<<dim3((OUT_DIM / 32) * 2), dim3(256), 0, stream>>>(
            x_Tb, indices, coeffs, out);
    } else {
        prep_kernel<<<dim3(COEFF_BLOCKS), dim3(256), 0, stream>>>(
            x, weights, x_Tb, coeffs, /*trans_blocks=*/0);
        dim3 grid(OUT_DIM / 256, BATCH / 32);
        logic_direct_kernel<<<grid, dim3(256), 0, stream>>>(
            x, indices, coeffs, out);
    }
}